// Round 5
// baseline (401.262 us; speedup 1.0000x reference)
//
#include <hip/hip_runtime.h>
#include <hip/hip_bf16.h>
#include <cstdint>
#include <cstddef>

// GCN 2-layer forward, MI355X (gfx950).
//   CSR build -> rowptr/colv + dinv
//   x -> (xh,xl) bf16 Dekker-split planes; W1,W2 -> transposed split planes
//   hs = bf16( dinv[m] * (x @ W1) )  3-term split-bf16 MFMA GEMM (swizzled LDS),
//                                    epilogue writes SLICE-MAJOR [NS][N][32]
//   h1 planes = split( relu(dinv*rowsum(hs) + b1) )   agg: XCD-pinned slices
//   gs = bf16( dinv[m] * (h1 @ W2) )  slice-major [4][N][32]
//   out = relu( dinv*rowsum(gs) + b2 )  fp32
//
// Agg locality scheme: hs stored slice-major; grid=(NSLICE, YB) so linear
// block id mod 8 == slice -> all blocks of a slice land on one XCD, whose
// 4 MB L2 fully caches that slice (50000*32*2B = 3.2 MB). Gathers become
// L2-local instead of riding the ~6.6 TB/s L2-miss fabric.

typedef short bf16x8 __attribute__((ext_vector_type(8)));
typedef float f32x4 __attribute__((ext_vector_type(4)));
typedef unsigned short u16;
typedef unsigned short u16x8 __attribute__((ext_vector_type(8)));

__device__ __forceinline__ float b2f(u16 u) {
    union { unsigned int i; float f; } c; c.i = ((unsigned int)u) << 16; return c.f;
}
__device__ __forceinline__ u16 f2b(float f) {
    union { float f; unsigned int i; } c; c.f = f;
    return (u16)((c.i + 0x7FFFu + ((c.i >> 16) & 1u)) >> 16);
}
// Dekker-style split: f ~= b2f(hi) + b2f(lo); hi = truncation (exact residual).
__device__ __forceinline__ void split2(float f, u16& hi, u16& lo) {
    union { float f; unsigned int i; } c; c.f = f;
    hi = (u16)(c.i >> 16);
    union { unsigned int i; float f; } h; h.i = c.i & 0xFFFF0000u;
    lo = f2b(f - h.f);
}

// ---------------- CSR build ----------------
__global__ __launch_bounds__(256) void k_fill_i32(int* __restrict__ p, int v, int n) {
    int i = blockIdx.x * 256 + threadIdx.x;
    if (i < n) p[i] = v;
}

__global__ __launch_bounds__(256) void k_count(const int* __restrict__ dst,
                                               int* __restrict__ cnt, int E) {
    int e = blockIdx.x * 256 + threadIdx.x;
    if (e < E) atomicAdd(&cnt[dst[e]], 1);
}

__global__ __launch_bounds__(256) void k_scan_block(const int* __restrict__ cnt,
                                                    int* __restrict__ rowptr,
                                                    int* __restrict__ partial,
                                                    float* __restrict__ dinv, int n) {
    __shared__ int s[256];
    int i = blockIdx.x * 256 + threadIdx.x;
    int v = (i < n) ? cnt[i] : 0;
    if (i < n) dinv[i] = rsqrtf((float)(v + 1));
    s[threadIdx.x] = v;
    __syncthreads();
    for (int off = 1; off < 256; off <<= 1) {
        int t = (threadIdx.x >= off) ? s[threadIdx.x - off] : 0;
        __syncthreads();
        s[threadIdx.x] += t;
        __syncthreads();
    }
    if (i < n) rowptr[i] = s[threadIdx.x] - v;
    if (threadIdx.x == 255) partial[blockIdx.x] = s[255];
}

__global__ __launch_bounds__(256) void k_scan_partial(int* __restrict__ partial, int nb) {
    __shared__ int s[256];
    int v = (threadIdx.x < nb) ? partial[threadIdx.x] : 0;
    s[threadIdx.x] = v;
    __syncthreads();
    for (int off = 1; off < 256; off <<= 1) {
        int t = (threadIdx.x >= off) ? s[threadIdx.x - off] : 0;
        __syncthreads();
        s[threadIdx.x] += t;
        __syncthreads();
    }
    if (threadIdx.x < nb) partial[threadIdx.x] = s[threadIdx.x] - v;
}

// also zeroes cnt (cursor reuse) — cnt dead after k_scan_block
__global__ __launch_bounds__(256) void k_scan_add(int* __restrict__ rowptr,
                                                  const int* __restrict__ partial,
                                                  int* __restrict__ cnt,
                                                  int n, int e) {
    int i = blockIdx.x * 256 + threadIdx.x;
    if (i < n) { rowptr[i] += partial[blockIdx.x]; cnt[i] = 0; }
    if (i == 0) rowptr[n] = e;
}

__global__ __launch_bounds__(256) void k_fill_col(const int* __restrict__ src,
                                                  const int* __restrict__ dst,
                                                  const int* __restrict__ rowptr,
                                                  int* __restrict__ cur,
                                                  int* __restrict__ colv, int E) {
    int e = blockIdx.x * 256 + threadIdx.x;
    if (e < E) {
        int d = dst[e];
        int p = rowptr[d] + atomicAdd(&cur[d], 1);
        colv[p] = src[e];
    }
}

// ---------------- fp32 -> split bf16 planes (elementwise, float4) ----------
__global__ __launch_bounds__(256) void k_split(const float* __restrict__ in,
                                               u16* __restrict__ hi,
                                               u16* __restrict__ lo, int n4) {
    int i = blockIdx.x * 256 + threadIdx.x;
    const int stride = gridDim.x * 256;
    for (; i < n4; i += stride) {
        float4 v = ((const float4*)in)[i];
        ushort4 h, l;
        split2(v.x, h.x, l.x); split2(v.y, h.y, l.y);
        split2(v.z, h.z, l.z); split2(v.w, h.w, l.w);
        ((ushort4*)hi)[i] = h;
        ((ushort4*)lo)[i] = l;
    }
}

// ---------------- transpose + split: src[R][C] -> dh/dl[C][R] --------------
__global__ __launch_bounds__(256) void k_tsplit(const float* __restrict__ src,
                                                u16* __restrict__ dh,
                                                u16* __restrict__ dl,
                                                int R, int C) {
    __shared__ float tile[64][65];
    int r0 = blockIdx.y * 64, c0 = blockIdx.x * 64;
    for (int i = threadIdx.x; i < 4096; i += 256) {
        int r = i >> 6, c = i & 63;
        tile[r][c] = src[(size_t)(r0 + r) * C + c0 + c];
    }
    __syncthreads();
    for (int i = threadIdx.x; i < 4096; i += 256) {
        int r = i >> 6, c = i & 63;
        float v = tile[c][r];
        u16 h, l;
        split2(v, h, l);
        size_t o = (size_t)(c0 + r) * R + r0 + c;
        dh[o] = h;
        dl[o] = l;
    }
}

// ---------------- pure-bf16 split GEMM (m97 structure + k-slot XOR swizzle) --
// C slice-major: C[(col>>5)*M + row][col&31] = bf16(scale[row] * acc).
// Tile 128x128, BK=32, 4 waves. LDS: 4 linear planes [128][32] bf16 = 32 KB,
// staged via global_load_lds width=16; k-slot XOR swizzle on BOTH global source
// address and ds_read address (G21 both-sides-or-neither).
__global__ __launch_bounds__(256) void k_gemm_split(const u16* __restrict__ Ah,
                                                    const u16* __restrict__ Al,
                                                    const u16* __restrict__ Bh,
                                                    const u16* __restrict__ Bl,
                                                    const float* __restrict__ scale,
                                                    u16* __restrict__ C,
                                                    int M, int K, int Nc) {
    __shared__ __align__(16) u16 lds[4 * 128 * 32];  // planes: Ah Al Bh Bl
    const int tid = threadIdx.x;
    const int m0 = blockIdx.x * 128, n0 = blockIdx.y * 128;
    const int w = tid >> 6, lane = tid & 63;
    const int wr = w >> 1, wc = w & 1;
    const int fr = lane & 15, kg = lane >> 4;

    f32x4 acc[4][4] = {};

    for (int k0 = 0; k0 < K; k0 += 32) {
#pragma unroll
        for (int c = 0; c < 8; ++c) {
            const int r = c * 4 + w;            // chunk id 0..31, wave-uniform
            const int plane = r >> 3;           // wave-uniform
            const int wch = (r & 7) * 64 + lane;
            const int row = wch >> 2;           // 0..127
            const int k16 = wch & 3;            // 16B slot in row
            const int kc = (k16 ^ ((row >> 1) & 3)) * 8;  // swizzled global k (shorts)
            const u16* gp;
            if (plane == 0) {
                int rg = m0 + row; rg = rg < M ? rg : M - 1;
                gp = Ah + (size_t)rg * K + k0 + kc;
            } else if (plane == 1) {
                int rg = m0 + row; rg = rg < M ? rg : M - 1;
                gp = Al + (size_t)rg * K + k0 + kc;
            } else if (plane == 2) {
                gp = Bh + (size_t)(n0 + row) * K + k0 + kc;
            } else {
                gp = Bl + (size_t)(n0 + row) * K + k0 + kc;
            }
            __builtin_amdgcn_global_load_lds(
                (const __attribute__((address_space(1))) void*)gp,
                (__attribute__((address_space(3))) void*)(lds + (size_t)r * 512),
                16, 0, 0);
        }
        __syncthreads();
        bf16x8 ah[4], al[4], bh[4], bl[4];
#pragma unroll
        for (int i = 0; i < 4; ++i) {
            const int ar = wr * 64 + i * 16 + fr;
            const int sa = (kg ^ ((ar >> 1) & 3)) * 8;
            ah[i] = *(const bf16x8*)&lds[0 * 4096 + ar * 32 + sa];
            al[i] = *(const bf16x8*)&lds[1 * 4096 + ar * 32 + sa];
            const int br = wc * 64 + i * 16 + fr;
            const int sb = (kg ^ ((br >> 1) & 3)) * 8;
            bh[i] = *(const bf16x8*)&lds[2 * 4096 + br * 32 + sb];
            bl[i] = *(const bf16x8*)&lds[3 * 4096 + br * 32 + sb];
        }
#pragma unroll
        for (int i = 0; i < 4; ++i)
#pragma unroll
            for (int j = 0; j < 4; ++j) {
                acc[i][j] = __builtin_amdgcn_mfma_f32_16x16x32_bf16(ah[i], bh[j], acc[i][j], 0, 0, 0);
                acc[i][j] = __builtin_amdgcn_mfma_f32_16x16x32_bf16(al[i], bh[j], acc[i][j], 0, 0, 0);
                acc[i][j] = __builtin_amdgcn_mfma_f32_16x16x32_bf16(ah[i], bl[j], acc[i][j], 0, 0, 0);
            }
        __syncthreads();
    }
    // C/D layout: col=lane&15, row=(lane>>4)*4+reg (m89/m91); slice-major store.
#pragma unroll
    for (int i = 0; i < 4; ++i) {
        const int rbase = m0 + wr * 64 + i * 16 + (lane >> 4) * 4;
#pragma unroll
        for (int r = 0; r < 4; ++r) {
            const int row = rbase + r;
            if (row < M) {
                const float s = scale[row];
#pragma unroll
                for (int j = 0; j < 4; ++j) {
                    const int col = n0 + wc * 64 + j * 16 + fr;
                    const size_t o = ((size_t)(col >> 5) * M + row) * 32 + (col & 31);
                    C[o] = f2b(acc[i][j][r] * s);
                }
            }
        }
    }
}

// ---------------- aggregation: XCD-pinned slice gather -----------------------
// Table slice-major [NSLICE][n][32] bf16 (pre-scaled by dinv[src]).
// grid=(NSLICE, YB): linear block id mod 8 == slice (NSLICE=8) or slice/slice+4
// (NSLICE=4) -> slice's 3.2 MB table pinned in that XCD's L2.
// Per wave: one dst node; 16 subgroups of 4 lanes, each reads one neighbor's
// 64B row-slice (16B/lane); 2-deep unroll; butterfly shfl_xor(4..32) combine.
// SPLIT: emit row-major hi/lo bf16 planes (feeds next GEMM); else fp32 out.
template <int NSLICE, bool SPLIT>
__global__ __launch_bounds__(256) void k_agg_sl(const u16* __restrict__ tbl0,
                                                const int* __restrict__ rowptr,
                                                const int* __restrict__ colv,
                                                const float* __restrict__ dinv,
                                                const float* __restrict__ bias,
                                                float* __restrict__ outf,
                                                u16* __restrict__ outh,
                                                u16* __restrict__ outl, int n) {
    constexpr int F = NSLICE * 32;
    const int slice = blockIdx.x;
    const int w = threadIdx.x >> 6, lane = threadIdx.x & 63;
    const int sub = lane >> 2, li = lane & 3;
    const int fb = li * 8;
    const u16* tbl = tbl0 + (size_t)slice * n * 32 + fb;
    const int stride = gridDim.y * 4;

    for (int wid = blockIdx.y * 4 + w; wid < n; wid += stride) {
        float acc[8] = {};
        const int p0 = rowptr[wid], p1 = rowptr[wid + 1];
        int p = p0 + sub;
        for (; p + 16 < p1; p += 32) {
            int s0 = colv[p], s1 = colv[p + 16];
            u16x8 v0 = *(const u16x8*)(tbl + (size_t)s0 * 32);
            u16x8 v1 = *(const u16x8*)(tbl + (size_t)s1 * 32);
#pragma unroll
            for (int j = 0; j < 8; ++j) acc[j] += b2f(v0[j]) + b2f(v1[j]);
        }
        if (p < p1) {
            u16x8 v = *(const u16x8*)(tbl + (size_t)colv[p] * 32);
#pragma unroll
            for (int j = 0; j < 8; ++j) acc[j] += b2f(v[j]);
        }
#pragma unroll
        for (int m = 4; m < 64; m <<= 1)
#pragma unroll
            for (int j = 0; j < 8; ++j) acc[j] += __shfl_xor(acc[j], m, 64);

        if (sub == 0) {
            u16x8 sv = *(const u16x8*)(tbl + (size_t)wid * 32);
            const float di = dinv[wid];
            float r[8];
#pragma unroll
            for (int j = 0; j < 8; ++j) {
                float t = di * (acc[j] + b2f(sv[j])) + bias[slice * 32 + fb + j];
                r[j] = t > 0.f ? t : 0.f;
            }
            const size_t o = (size_t)wid * F + slice * 32 + fb;
            if constexpr (SPLIT) {
                u16x8 hv, lv;
#pragma unroll
                for (int j = 0; j < 8; ++j) { u16 h, l; split2(r[j], h, l); hv[j] = h; lv[j] = l; }
                *(u16x8*)(outh + o) = hv;
                *(u16x8*)(outl + o) = lv;
            } else {
                float* op = outf + o;
                *(float4*)(op)     = make_float4(r[0], r[1], r[2], r[3]);
                *(float4*)(op + 4) = make_float4(r[4], r[5], r[6], r[7]);
            }
        }
    }
}

extern "C" void kernel_launch(void* const* d_in, const int* in_sizes, int n_in,
                              void* d_out, int out_size, void* d_ws, size_t ws_size,
                              hipStream_t stream) {
    const float* x  = (const float*)d_in[0];
    const int*   ei = (const int*)d_in[1];
    const float* W1 = (const float*)d_in[2];
    const float* b1 = (const float*)d_in[3];
    const float* W2 = (const float*)d_in[4];
    const float* b2 = (const float*)d_in[5];

    const int HID = in_sizes[3];            // 256
    const int IN  = in_sizes[2] / HID;      // 256
    const int OUT = in_sizes[5];            // 128
    const int N   = in_sizes[0] / IN;       // 50000
    const int E   = in_sizes[1] / 2;        // 800000

    const int* src = ei;
    const int* dst = ei + E;

    char* wsb = (char*)d_ws;
    size_t off = 0;
    auto carve = [&](size_t bytes) -> char* {
        char* p = wsb + off;
        off += (bytes + 255) & ~(size_t)255;
        return p;
    };
    u16* xh  = (u16*)carve((size_t)N * IN * 2);   // also h1h
    u16* xl  = (u16*)carve((size_t)N * IN * 2);   // also h1l
    u16* hsb = (u16*)carve((size_t)N * HID * 2);  // slice-major [8][N][32]
    u16* gsb = (u16*)carve((size_t)N * OUT * 2);  // slice-major [4][N][32]
    float* dinv   = (float*)carve((size_t)N * 4);
    int*   rowptr = (int*)carve((size_t)(N + 1) * 4);
    int*   cnt    = (int*)carve((size_t)N * 4);
    int*   part   = (int*)carve(1024);
    int*   colv   = (int*)carve((size_t)E * 4);
    u16* W1Th = (u16*)carve((size_t)IN * HID * 2);
    u16* W1Tl = (u16*)carve((size_t)IN * HID * 2);
    u16* W2Th = (u16*)carve((size_t)HID * OUT * 2);
    u16* W2Tl = (u16*)carve((size_t)HID * OUT * 2);
    u16* h1h = xh;  // reuse: x planes dead after gemm1
    u16* h1l = xl;
    (void)ws_size; (void)n_in; (void)out_size;

    const int nbN = (N + 255) / 256;   // 196 (<=256 required by k_scan_partial)
    const int nbE = (E + 255) / 256;

    // CSR + dinv
    k_fill_i32<<<nbN, 256, 0, stream>>>(cnt, 0, N);
    k_count<<<nbE, 256, 0, stream>>>(dst, cnt, E);
    k_scan_block<<<nbN, 256, 0, stream>>>(cnt, rowptr, part, dinv, N);
    k_scan_partial<<<1, 256, 0, stream>>>(part, nbN);
    k_scan_add<<<nbN, 256, 0, stream>>>(rowptr, part, cnt, N, E);
    k_fill_col<<<nbE, 256, 0, stream>>>(src, dst, rowptr, cnt, colv, E);

    // operand prep
    k_split<<<2048, 256, 0, stream>>>(x, xh, xl, (N * IN) / 4);
    k_tsplit<<<dim3(HID / 64, IN / 64), 256, 0, stream>>>(W1, W1Th, W1Tl, IN, HID);
    k_tsplit<<<dim3(OUT / 64, HID / 64), 256, 0, stream>>>(W2, W2Th, W2Tl, HID, OUT);

    // layer 1
    k_gemm_split<<<dim3((N + 127) / 128, HID / 128), 256, 0, stream>>>(
        xh, xl, W1Th, W1Tl, dinv, hsb, N, IN, HID);
    k_agg_sl<8, true><<<dim3(8, 512), 256, 0, stream>>>(
        hsb, rowptr, colv, dinv, b1, nullptr, h1h, h1l, N);
    // layer 2
    k_gemm_split<<<dim3((N + 127) / 128, OUT / 128), 256, 0, stream>>>(
        h1h, h1l, W2Th, W2Tl, dinv, gsb, N, HID, OUT);
    k_agg_sl<4, false><<<dim3(4, 1024), 256, 0, stream>>>(
        gsb, rowptr, colv, dinv, b2, (float*)d_out, nullptr, nullptr, N);
}

// Round 6
// 279.537 us; speedup vs baseline: 1.4354x; 1.4354x over previous
//
#include <hip/hip_runtime.h>
#include <hip/hip_bf16.h>
#include <cstdint>
#include <cstddef>

// GCN 2-layer forward, MI355X (gfx950).
//   CSR build -> rowptr/colv + dinv
//   x -> (xh,xl) bf16 Dekker-split planes; W1,W2 -> transposed split planes
//   hs = bf16( dinv[m] * (x @ W1) )  3-term split-bf16 MFMA GEMM (swizzled LDS),
//                                    epilogue writes SLICE-MAJOR [NS][N][32]
//   h1 planes = split( relu(dinv*rowsum(hs) + b1) )   agg: XCD-pinned slices
//   gs = bf16( dinv[m] * (h1 @ W2) )  slice-major [4][N][32]
//   out = relu( dinv*rowsum(gs) + b2 )  fp32
//
// Agg: hs slice-major; grid=(NSLICE,YB) -> linear block id mod 8 == slice,
// pinning each 3.2 MB slice in one XCD's 4 MB L2 (R5: FETCH 187->60 MB,
// mechanism verified). R6 fixes R5's overhead: one 4-LANE SUBGROUP per
// (node,slice) — no butterfly, no per-node wave, 64 nodes/block.

typedef short bf16x8 __attribute__((ext_vector_type(8)));
typedef float f32x4 __attribute__((ext_vector_type(4)));
typedef unsigned short u16;
typedef unsigned short u16x8 __attribute__((ext_vector_type(8)));

__device__ __forceinline__ float b2f(u16 u) {
    union { unsigned int i; float f; } c; c.i = ((unsigned int)u) << 16; return c.f;
}
__device__ __forceinline__ u16 f2b(float f) {
    union { float f; unsigned int i; } c; c.f = f;
    return (u16)((c.i + 0x7FFFu + ((c.i >> 16) & 1u)) >> 16);
}
// Dekker-style split: f ~= b2f(hi) + b2f(lo); hi = truncation (exact residual).
__device__ __forceinline__ void split2(float f, u16& hi, u16& lo) {
    union { float f; unsigned int i; } c; c.f = f;
    hi = (u16)(c.i >> 16);
    union { unsigned int i; float f; } h; h.i = c.i & 0xFFFF0000u;
    lo = f2b(f - h.f);
}

// ---------------- CSR build ----------------
__global__ __launch_bounds__(256) void k_fill_i32(int* __restrict__ p, int v, int n) {
    int i = blockIdx.x * 256 + threadIdx.x;
    if (i < n) p[i] = v;
}

__global__ __launch_bounds__(256) void k_count(const int* __restrict__ dst,
                                               int* __restrict__ cnt, int E) {
    int e = blockIdx.x * 256 + threadIdx.x;
    if (e < E) atomicAdd(&cnt[dst[e]], 1);
}

__global__ __launch_bounds__(256) void k_scan_block(const int* __restrict__ cnt,
                                                    int* __restrict__ rowptr,
                                                    int* __restrict__ partial,
                                                    float* __restrict__ dinv, int n) {
    __shared__ int s[256];
    int i = blockIdx.x * 256 + threadIdx.x;
    int v = (i < n) ? cnt[i] : 0;
    if (i < n) dinv[i] = rsqrtf((float)(v + 1));
    s[threadIdx.x] = v;
    __syncthreads();
    for (int off = 1; off < 256; off <<= 1) {
        int t = (threadIdx.x >= off) ? s[threadIdx.x - off] : 0;
        __syncthreads();
        s[threadIdx.x] += t;
        __syncthreads();
    }
    if (i < n) rowptr[i] = s[threadIdx.x] - v;
    if (threadIdx.x == 255) partial[blockIdx.x] = s[255];
}

__global__ __launch_bounds__(256) void k_scan_partial(int* __restrict__ partial, int nb) {
    __shared__ int s[256];
    int v = (threadIdx.x < nb) ? partial[threadIdx.x] : 0;
    s[threadIdx.x] = v;
    __syncthreads();
    for (int off = 1; off < 256; off <<= 1) {
        int t = (threadIdx.x >= off) ? s[threadIdx.x - off] : 0;
        __syncthreads();
        s[threadIdx.x] += t;
        __syncthreads();
    }
    if (threadIdx.x < nb) partial[threadIdx.x] = s[threadIdx.x] - v;
}

// also zeroes cnt (cursor reuse) — cnt dead after k_scan_block
__global__ __launch_bounds__(256) void k_scan_add(int* __restrict__ rowptr,
                                                  const int* __restrict__ partial,
                                                  int* __restrict__ cnt,
                                                  int n, int e) {
    int i = blockIdx.x * 256 + threadIdx.x;
    if (i < n) { rowptr[i] += partial[blockIdx.x]; cnt[i] = 0; }
    if (i == 0) rowptr[n] = e;
}

__global__ __launch_bounds__(256) void k_fill_col(const int* __restrict__ src,
                                                  const int* __restrict__ dst,
                                                  const int* __restrict__ rowptr,
                                                  int* __restrict__ cur,
                                                  int* __restrict__ colv, int E) {
    int e = blockIdx.x * 256 + threadIdx.x;
    if (e < E) {
        int d = dst[e];
        int p = rowptr[d] + atomicAdd(&cur[d], 1);
        colv[p] = src[e];
    }
}

// ---------------- fp32 -> split bf16 planes (elementwise, float4) ----------
__global__ __launch_bounds__(256) void k_split(const float* __restrict__ in,
                                               u16* __restrict__ hi,
                                               u16* __restrict__ lo, int n4) {
    int i = blockIdx.x * 256 + threadIdx.x;
    const int stride = gridDim.x * 256;
    for (; i < n4; i += stride) {
        float4 v = ((const float4*)in)[i];
        ushort4 h, l;
        split2(v.x, h.x, l.x); split2(v.y, h.y, l.y);
        split2(v.z, h.z, l.z); split2(v.w, h.w, l.w);
        ((ushort4*)hi)[i] = h;
        ((ushort4*)lo)[i] = l;
    }
}

// ---------------- transpose + split: src[R][C] -> dh/dl[C][R] --------------
__global__ __launch_bounds__(256) void k_tsplit(const float* __restrict__ src,
                                                u16* __restrict__ dh,
                                                u16* __restrict__ dl,
                                                int R, int C) {
    __shared__ float tile[64][65];
    int r0 = blockIdx.y * 64, c0 = blockIdx.x * 64;
    for (int i = threadIdx.x; i < 4096; i += 256) {
        int r = i >> 6, c = i & 63;
        tile[r][c] = src[(size_t)(r0 + r) * C + c0 + c];
    }
    __syncthreads();
    for (int i = threadIdx.x; i < 4096; i += 256) {
        int r = i >> 6, c = i & 63;
        float v = tile[c][r];
        u16 h, l;
        split2(v, h, l);
        size_t o = (size_t)(c0 + r) * R + r0 + c;
        dh[o] = h;
        dl[o] = l;
    }
}

// ---------------- pure-bf16 split GEMM (m97 structure + k-slot XOR swizzle) --
// C slice-major: C[(col>>5)*M + row][col&31] = bf16(scale[row] * acc).
// Tile 128x128, BK=32, 4 waves. LDS: 4 linear planes [128][32] bf16 = 32 KB,
// staged via global_load_lds width=16; k-slot XOR swizzle on BOTH global source
// address and ds_read address (G21 both-sides-or-neither).
__global__ __launch_bounds__(256) void k_gemm_split(const u16* __restrict__ Ah,
                                                    const u16* __restrict__ Al,
                                                    const u16* __restrict__ Bh,
                                                    const u16* __restrict__ Bl,
                                                    const float* __restrict__ scale,
                                                    u16* __restrict__ C,
                                                    int M, int K, int Nc) {
    __shared__ __align__(16) u16 lds[4 * 128 * 32];  // planes: Ah Al Bh Bl
    const int tid = threadIdx.x;
    const int m0 = blockIdx.x * 128, n0 = blockIdx.y * 128;
    const int w = tid >> 6, lane = tid & 63;
    const int wr = w >> 1, wc = w & 1;
    const int fr = lane & 15, kg = lane >> 4;

    f32x4 acc[4][4] = {};

    for (int k0 = 0; k0 < K; k0 += 32) {
#pragma unroll
        for (int c = 0; c < 8; ++c) {
            const int r = c * 4 + w;            // chunk id 0..31, wave-uniform
            const int plane = r >> 3;           // wave-uniform
            const int wch = (r & 7) * 64 + lane;
            const int row = wch >> 2;           // 0..127
            const int k16 = wch & 3;            // 16B slot in row
            const int kc = (k16 ^ ((row >> 1) & 3)) * 8;  // swizzled global k (shorts)
            const u16* gp;
            if (plane == 0) {
                int rg = m0 + row; rg = rg < M ? rg : M - 1;
                gp = Ah + (size_t)rg * K + k0 + kc;
            } else if (plane == 1) {
                int rg = m0 + row; rg = rg < M ? rg : M - 1;
                gp = Al + (size_t)rg * K + k0 + kc;
            } else if (plane == 2) {
                gp = Bh + (size_t)(n0 + row) * K + k0 + kc;
            } else {
                gp = Bl + (size_t)(n0 + row) * K + k0 + kc;
            }
            __builtin_amdgcn_global_load_lds(
                (const __attribute__((address_space(1))) void*)gp,
                (__attribute__((address_space(3))) void*)(lds + (size_t)r * 512),
                16, 0, 0);
        }
        __syncthreads();
        bf16x8 ah[4], al[4], bh[4], bl[4];
#pragma unroll
        for (int i = 0; i < 4; ++i) {
            const int ar = wr * 64 + i * 16 + fr;
            const int sa = (kg ^ ((ar >> 1) & 3)) * 8;
            ah[i] = *(const bf16x8*)&lds[0 * 4096 + ar * 32 + sa];
            al[i] = *(const bf16x8*)&lds[1 * 4096 + ar * 32 + sa];
            const int br = wc * 64 + i * 16 + fr;
            const int sb = (kg ^ ((br >> 1) & 3)) * 8;
            bh[i] = *(const bf16x8*)&lds[2 * 4096 + br * 32 + sb];
            bl[i] = *(const bf16x8*)&lds[3 * 4096 + br * 32 + sb];
        }
#pragma unroll
        for (int i = 0; i < 4; ++i)
#pragma unroll
            for (int j = 0; j < 4; ++j) {
                acc[i][j] = __builtin_amdgcn_mfma_f32_16x16x32_bf16(ah[i], bh[j], acc[i][j], 0, 0, 0);
                acc[i][j] = __builtin_amdgcn_mfma_f32_16x16x32_bf16(al[i], bh[j], acc[i][j], 0, 0, 0);
                acc[i][j] = __builtin_amdgcn_mfma_f32_16x16x32_bf16(ah[i], bl[j], acc[i][j], 0, 0, 0);
            }
        __syncthreads();
    }
    // C/D layout: col=lane&15, row=(lane>>4)*4+reg (m89/m91); slice-major store.
#pragma unroll
    for (int i = 0; i < 4; ++i) {
        const int rbase = m0 + wr * 64 + i * 16 + (lane >> 4) * 4;
#pragma unroll
        for (int r = 0; r < 4; ++r) {
            const int row = rbase + r;
            if (row < M) {
                const float s = scale[row];
#pragma unroll
                for (int j = 0; j < 4; ++j) {
                    const int col = n0 + wc * 64 + j * 16 + fr;
                    const size_t o = ((size_t)(col >> 5) * M + row) * 32 + (col & 31);
                    C[o] = f2b(acc[i][j][r] * s);
                }
            }
        }
    }
}

// ---------------- aggregation: XCD-pinned slices, subgroup-per-node ----------
// Table slice-major [NSLICE][n][32] bf16 (pre-scaled by dinv[src]).
// grid=(NSLICE, ceil(n/64)): linear block id mod 8 == slice (NSLICE=8) or
// slice/slice+4 (NSLICE=4) -> slice pinned in an XCD's L2.
// One 4-lane subgroup per (node,slice): lane li owns 8 features (16B reads),
// sequential edge loop (2-deep unroll), NO cross-lane reduction.
// SPLIT: emit row-major hi/lo bf16 planes (feeds next GEMM); else fp32 out.
template <int NSLICE, bool SPLIT>
__global__ __launch_bounds__(256) void k_agg_sub(const u16* __restrict__ tbl0,
                                                 const int* __restrict__ rowptr,
                                                 const int* __restrict__ colv,
                                                 const float* __restrict__ dinv,
                                                 const float* __restrict__ bias,
                                                 float* __restrict__ outf,
                                                 u16* __restrict__ outh,
                                                 u16* __restrict__ outl, int n) {
    constexpr int F = NSLICE * 32;
    const int slice = blockIdx.x;
    const int g = threadIdx.x >> 2;      // subgroup 0..63 = node within block
    const int li = threadIdx.x & 3;
    const int fb = li * 8;               // feature offset within slice
    const int wid = blockIdx.y * 64 + g;
    if (wid >= n) return;
    const u16* tbl = tbl0 + (size_t)slice * n * 32 + fb;

    float acc[8];
    {   // self row (pre-scaled by dinv[wid] in GEMM epilogue)
        u16x8 v = *(const u16x8*)(tbl + (size_t)wid * 32);
#pragma unroll
        for (int j = 0; j < 8; ++j) acc[j] = b2f(v[j]);
    }
    const int p0 = rowptr[wid], p1 = rowptr[wid + 1];
    int p = p0;
    for (; p + 2 <= p1; p += 2) {
        int s0 = colv[p], s1 = colv[p + 1];
        u16x8 v0 = *(const u16x8*)(tbl + (size_t)s0 * 32);
        u16x8 v1 = *(const u16x8*)(tbl + (size_t)s1 * 32);
#pragma unroll
        for (int j = 0; j < 8; ++j) acc[j] += b2f(v0[j]) + b2f(v1[j]);
    }
    if (p < p1) {
        u16x8 v = *(const u16x8*)(tbl + (size_t)colv[p] * 32);
#pragma unroll
        for (int j = 0; j < 8; ++j) acc[j] += b2f(v[j]);
    }
    const float di = dinv[wid];
    float r[8];
#pragma unroll
    for (int j = 0; j < 8; ++j) {
        float t = di * acc[j] + bias[slice * 32 + fb + j];
        r[j] = t > 0.f ? t : 0.f;
    }
    const size_t o = (size_t)wid * F + slice * 32 + fb;
    if constexpr (SPLIT) {
        u16x8 hv, lv;
#pragma unroll
        for (int j = 0; j < 8; ++j) { u16 h, l; split2(r[j], h, l); hv[j] = h; lv[j] = l; }
        *(u16x8*)(outh + o) = hv;
        *(u16x8*)(outl + o) = lv;
    } else {
        float* op = outf + o;
        *(float4*)(op)     = make_float4(r[0], r[1], r[2], r[3]);
        *(float4*)(op + 4) = make_float4(r[4], r[5], r[6], r[7]);
    }
}

extern "C" void kernel_launch(void* const* d_in, const int* in_sizes, int n_in,
                              void* d_out, int out_size, void* d_ws, size_t ws_size,
                              hipStream_t stream) {
    const float* x  = (const float*)d_in[0];
    const int*   ei = (const int*)d_in[1];
    const float* W1 = (const float*)d_in[2];
    const float* b1 = (const float*)d_in[3];
    const float* W2 = (const float*)d_in[4];
    const float* b2 = (const float*)d_in[5];

    const int HID = in_sizes[3];            // 256
    const int IN  = in_sizes[2] / HID;      // 256
    const int OUT = in_sizes[5];            // 128
    const int N   = in_sizes[0] / IN;       // 50000
    const int E   = in_sizes[1] / 2;        // 800000

    const int* src = ei;
    const int* dst = ei + E;

    char* wsb = (char*)d_ws;
    size_t off = 0;
    auto carve = [&](size_t bytes) -> char* {
        char* p = wsb + off;
        off += (bytes + 255) & ~(size_t)255;
        return p;
    };
    u16* xh  = (u16*)carve((size_t)N * IN * 2);   // also h1h
    u16* xl  = (u16*)carve((size_t)N * IN * 2);   // also h1l
    u16* hsb = (u16*)carve((size_t)N * HID * 2);  // slice-major [8][N][32]
    u16* gsb = (u16*)carve((size_t)N * OUT * 2);  // slice-major [4][N][32]
    float* dinv   = (float*)carve((size_t)N * 4);
    int*   rowptr = (int*)carve((size_t)(N + 1) * 4);
    int*   cnt    = (int*)carve((size_t)N * 4);
    int*   part   = (int*)carve(1024);
    int*   colv   = (int*)carve((size_t)E * 4);
    u16* W1Th = (u16*)carve((size_t)IN * HID * 2);
    u16* W1Tl = (u16*)carve((size_t)IN * HID * 2);
    u16* W2Th = (u16*)carve((size_t)HID * OUT * 2);
    u16* W2Tl = (u16*)carve((size_t)HID * OUT * 2);
    u16* h1h = xh;  // reuse: x planes dead after gemm1
    u16* h1l = xl;
    (void)ws_size; (void)n_in; (void)out_size;

    const int nbN = (N + 255) / 256;   // 196 (<=256 required by k_scan_partial)
    const int nbE = (E + 255) / 256;
    const int ybN = (N + 63) / 64;     // 782: one subgroup per node

    // CSR + dinv
    k_fill_i32<<<nbN, 256, 0, stream>>>(cnt, 0, N);
    k_count<<<nbE, 256, 0, stream>>>(dst, cnt, E);
    k_scan_block<<<nbN, 256, 0, stream>>>(cnt, rowptr, part, dinv, N);
    k_scan_partial<<<1, 256, 0, stream>>>(part, nbN);
    k_scan_add<<<nbN, 256, 0, stream>>>(rowptr, part, cnt, N, E);
    k_fill_col<<<nbE, 256, 0, stream>>>(src, dst, rowptr, cnt, colv, E);

    // operand prep
    k_split<<<2048, 256, 0, stream>>>(x, xh, xl, (N * IN) / 4);
    k_tsplit<<<dim3(HID / 64, IN / 64), 256, 0, stream>>>(W1, W1Th, W1Tl, IN, HID);
    k_tsplit<<<dim3(OUT / 64, HID / 64), 256, 0, stream>>>(W2, W2Th, W2Tl, HID, OUT);

    // layer 1
    k_gemm_split<<<dim3((N + 127) / 128, HID / 128), 256, 0, stream>>>(
        xh, xl, W1Th, W1Tl, dinv, hsb, N, IN, HID);
    k_agg_sub<8, true><<<dim3(8, ybN), 256, 0, stream>>>(
        hsb, rowptr, colv, dinv, b1, nullptr, h1h, h1l, N);
    // layer 2
    k_gemm_split<<<dim3((N + 127) / 128, OUT / 128), 256, 0, stream>>>(
        h1h, h1l, W2Th, W2Tl, dinv, gsb, N, HID, OUT);
    k_agg_sub<4, false><<<dim3(4, ybN), 256, 0, stream>>>(
        gsb, rowptr, colv, dinv, b2, (float*)d_out, nullptr, nullptr, N);
}

// Round 8
// 252.267 us; speedup vs baseline: 1.5906x; 1.1081x over previous
//
#include <hip/hip_runtime.h>
#include <hip/hip_bf16.h>
#include <cstdint>
#include <cstddef>

// GCN 2-layer forward, MI355X (gfx950).
//   CSR build -> rowptr/colv + dinv
//   x -> (xh,xl) fp16 Dekker-split planes; W1,W2 -> transposed fp16-hi planes
//   hs = fp16( dinv[m] * (x @ W1h) )   2-term fp16 MFMA GEMM (a = ah+al exact),
//                                      slice-major [4][N][64] fp16
//   h1 planes = fp16split( relu(dinv*rowsum(hs) + b1) )
//   gs = fp16( dinv[m] * (h1 @ W2h) )  slice-major [2][N][64]
//   out = relu( dinv*rowsum(gs) + b2 )  fp32
//
// Agg: 128-byte gather granules (64 fp16 feats, 8-lane subgroup x 16B) —
// one L1-line event per edge-visit instead of two 64B events (R6 showed the
// bound is granule-event rate ~10 B/cyc/CU, not bytes). Slice-major tables +
// blockIdx%NXCD pinning keeps most gathers XCD-L2-local (R5/R6: FETCH 187->81MB).

typedef float f32x4 __attribute__((ext_vector_type(4)));
typedef _Float16 f16x8 __attribute__((ext_vector_type(8)));
typedef _Float16 f16x4 __attribute__((ext_vector_type(4)));
typedef unsigned short u16;

struct h2 { _Float16 h, l; };
// fp16 Dekker split: f = (float)h + (float)l + O(2^-22 rel)
__device__ __forceinline__ h2 split2h(float f) {
    h2 r;
    r.h = (_Float16)f;
    r.l = (_Float16)(f - (float)r.h);
    return r;
}

// ---------------- CSR build ----------------
__global__ __launch_bounds__(256) void k_fill_i32(int* __restrict__ p, int v, int n) {
    int i = blockIdx.x * 256 + threadIdx.x;
    if (i < n) p[i] = v;
}

__global__ __launch_bounds__(256) void k_count(const int* __restrict__ dst,
                                               int* __restrict__ cnt, int E) {
    int e = blockIdx.x * 256 + threadIdx.x;
    if (e < E) atomicAdd(&cnt[dst[e]], 1);
}

__global__ __launch_bounds__(256) void k_scan_block(const int* __restrict__ cnt,
                                                    int* __restrict__ rowptr,
                                                    int* __restrict__ partial,
                                                    float* __restrict__ dinv, int n) {
    __shared__ int s[256];
    int i = blockIdx.x * 256 + threadIdx.x;
    int v = (i < n) ? cnt[i] : 0;
    if (i < n) dinv[i] = rsqrtf((float)(v + 1));
    s[threadIdx.x] = v;
    __syncthreads();
    for (int off = 1; off < 256; off <<= 1) {
        int t = (threadIdx.x >= off) ? s[threadIdx.x - off] : 0;
        __syncthreads();
        s[threadIdx.x] += t;
        __syncthreads();
    }
    if (i < n) rowptr[i] = s[threadIdx.x] - v;
    if (threadIdx.x == 255) partial[blockIdx.x] = s[255];
}

__global__ __launch_bounds__(256) void k_scan_partial(int* __restrict__ partial, int nb) {
    __shared__ int s[256];
    int v = (threadIdx.x < nb) ? partial[threadIdx.x] : 0;
    s[threadIdx.x] = v;
    __syncthreads();
    for (int off = 1; off < 256; off <<= 1) {
        int t = (threadIdx.x >= off) ? s[threadIdx.x - off] : 0;
        __syncthreads();
        s[threadIdx.x] += t;
        __syncthreads();
    }
    if (threadIdx.x < nb) partial[threadIdx.x] = s[threadIdx.x] - v;
}

// also zeroes cnt (cursor reuse) — cnt dead after k_scan_block
__global__ __launch_bounds__(256) void k_scan_add(int* __restrict__ rowptr,
                                                  const int* __restrict__ partial,
                                                  int* __restrict__ cnt,
                                                  int n, int e) {
    int i = blockIdx.x * 256 + threadIdx.x;
    if (i < n) { rowptr[i] += partial[blockIdx.x]; cnt[i] = 0; }
    if (i == 0) rowptr[n] = e;
}

__global__ __launch_bounds__(256) void k_fill_col(const int* __restrict__ src,
                                                  const int* __restrict__ dst,
                                                  const int* __restrict__ rowptr,
                                                  int* __restrict__ cur,
                                                  int* __restrict__ colv, int E) {
    int e = blockIdx.x * 256 + threadIdx.x;
    if (e < E) {
        int d = dst[e];
        int p = rowptr[d] + atomicAdd(&cur[d], 1);
        colv[p] = src[e];
    }
}

// ---------------- fp32 -> fp16 split planes (elementwise, float4) ----------
__global__ __launch_bounds__(256) void k_split(const float* __restrict__ in,
                                               _Float16* __restrict__ hi,
                                               _Float16* __restrict__ lo, int n4) {
    int i = blockIdx.x * 256 + threadIdx.x;
    const int stride = gridDim.x * 256;
    for (; i < n4; i += stride) {
        float4 v = ((const float4*)in)[i];
        h2 a = split2h(v.x), b = split2h(v.y), c = split2h(v.z), d = split2h(v.w);
        f16x4 h, l;
        h[0] = a.h; h[1] = b.h; h[2] = c.h; h[3] = d.h;
        l[0] = a.l; l[1] = b.l; l[2] = c.l; l[3] = d.l;
        *(f16x4*)(hi + (size_t)i * 4) = h;
        *(f16x4*)(lo + (size_t)i * 4) = l;
    }
}

// ---------------- transpose + fp16 cast: src[R][C] -> dh[C][R] -------------
__global__ __launch_bounds__(256) void k_thalf(const float* __restrict__ src,
                                               _Float16* __restrict__ dh,
                                               int R, int C) {
    __shared__ float tile[64][65];
    int r0 = blockIdx.y * 64, c0 = blockIdx.x * 64;
    for (int i = threadIdx.x; i < 4096; i += 256) {
        int r = i >> 6, c = i & 63;
        tile[r][c] = src[(size_t)(r0 + r) * C + c0 + c];
    }
    __syncthreads();
    for (int i = threadIdx.x; i < 4096; i += 256) {
        int r = i >> 6, c = i & 63;
        dh[(size_t)(c0 + r) * R + r0 + c] = (_Float16)tile[c][r];
    }
}

// ---------------- 2-term fp16 split GEMM (m97 structure + k-slot swizzle) ----
// C = fp16(scale[m] * (A @ Bh^T)) with A = Ah+Al (exact to 2^-22), B hi-only.
// Tile 128x128, BK=32, 4 waves. LDS: 3 linear planes [128][32] fp16 = 24 KB,
// staged via global_load_lds width=16; k-slot XOR swizzle on BOTH the global
// source address and the ds_read address (G21 both-sides-or-neither).
// Epilogue: slice-major store C[(col>>6)*M + row][col&63].
__global__ __launch_bounds__(256) void k_gemm_split(const _Float16* __restrict__ Ah,
                                                    const _Float16* __restrict__ Al,
                                                    const _Float16* __restrict__ Bh,
                                                    const float* __restrict__ scale,
                                                    _Float16* __restrict__ C,
                                                    int M, int K, int Nc) {
    __shared__ __align__(16) _Float16 lds[3 * 128 * 32];  // planes: Ah Al Bh
    const int tid = threadIdx.x;
    const int m0 = blockIdx.x * 128, n0 = blockIdx.y * 128;
    const int w = tid >> 6, lane = tid & 63;
    const int wr = w >> 1, wc = w & 1;
    const int fr = lane & 15, kg = lane >> 4;

    f32x4 acc[4][4] = {};

    for (int k0 = 0; k0 < K; k0 += 32) {
#pragma unroll
        for (int c = 0; c < 6; ++c) {
            const int r = c * 4 + w;            // chunk id 0..23, wave-uniform
            const int plane = r >> 3;           // 0=Ah 1=Al 2=Bh, wave-uniform
            const int wch = (r & 7) * 64 + lane;
            const int row = wch >> 2;           // 0..127
            const int k16 = wch & 3;            // 16B slot in row
            const int kc = (k16 ^ ((row >> 1) & 3)) * 8;  // swizzled global k
            const _Float16* gp;
            if (plane == 0) {
                int rg = m0 + row; rg = rg < M ? rg : M - 1;
                gp = Ah + (size_t)rg * K + k0 + kc;
            } else if (plane == 1) {
                int rg = m0 + row; rg = rg < M ? rg : M - 1;
                gp = Al + (size_t)rg * K + k0 + kc;
            } else {
                gp = Bh + (size_t)(n0 + row) * K + k0 + kc;
            }
            __builtin_amdgcn_global_load_lds(
                (const __attribute__((address_space(1))) void*)gp,
                (__attribute__((address_space(3))) void*)(lds + (size_t)r * 512),
                16, 0, 0);
        }
        __syncthreads();
        f16x8 ah[4], al[4], bh[4];
#pragma unroll
        for (int i = 0; i < 4; ++i) {
            const int ar = wr * 64 + i * 16 + fr;
            const int sa = (kg ^ ((ar >> 1) & 3)) * 8;
            ah[i] = *(const f16x8*)&lds[0 * 4096 + ar * 32 + sa];
            al[i] = *(const f16x8*)&lds[1 * 4096 + ar * 32 + sa];
            const int br = wc * 64 + i * 16 + fr;
            const int sb = (kg ^ ((br >> 1) & 3)) * 8;
            bh[i] = *(const f16x8*)&lds[2 * 4096 + br * 32 + sb];
        }
#pragma unroll
        for (int i = 0; i < 4; ++i)
#pragma unroll
            for (int j = 0; j < 4; ++j) {
                acc[i][j] = __builtin_amdgcn_mfma_f32_16x16x32_f16(ah[i], bh[j], acc[i][j], 0, 0, 0);
                acc[i][j] = __builtin_amdgcn_mfma_f32_16x16x32_f16(al[i], bh[j], acc[i][j], 0, 0, 0);
            }
        __syncthreads();
    }
    // C/D layout: col=lane&15, row=(lane>>4)*4+reg (m89/m91); slice-major store.
#pragma unroll
    for (int i = 0; i < 4; ++i) {
        const int rbase = m0 + wr * 64 + i * 16 + (lane >> 4) * 4;
#pragma unroll
        for (int r = 0; r < 4; ++r) {
            const int row = rbase + r;
            if (row < M) {
                const float s = scale[row];
#pragma unroll
                for (int j = 0; j < 4; ++j) {
                    const int col = n0 + wc * 64 + j * 16 + fr;
                    const size_t o = ((size_t)(col >> 6) * M + row) * 64 + (col & 63);
                    C[o] = (_Float16)(acc[i][j][r] * s);
                }
            }
        }
    }
}

// ---------------- aggregation: 128B granules, XCD-pinned slices --------------
// Table slice-major [NSLICE][n][64] fp16 (pre-scaled by dinv[src]).
// grid=(NSLICE, ceil(n/32)): linear block id mod 8 keeps each slice on a small
// fixed set of XCDs. One 8-LANE subgroup per (node,slice): lane li owns 8
// feats (16B); one full 128B L1 line per edge-visit; 4-deep unroll for MLP.
// SPLIT: emit row-major fp16 hi/lo planes (feeds next GEMM); else fp32 out.
template <int NSLICE, bool SPLIT>
__global__ __launch_bounds__(256) void k_agg_gr(const _Float16* __restrict__ tbl0,
                                                const int* __restrict__ rowptr,
                                                const int* __restrict__ colv,
                                                const float* __restrict__ dinv,
                                                const float* __restrict__ bias,
                                                float* __restrict__ outf,
                                                _Float16* __restrict__ outh,
                                                _Float16* __restrict__ outl, int n) {
    constexpr int F = NSLICE * 64;
    const int slice = blockIdx.x;
    const int g = threadIdx.x >> 3;      // subgroup 0..31 = node within block
    const int li = threadIdx.x & 7;
    const int fb = li * 8;               // feature offset within slice
    const int wid = blockIdx.y * 32 + g;
    if (wid >= n) return;
    const _Float16* tbl = tbl0 + (size_t)slice * n * 64 + fb;

    float acc[8];
    {   // self row (pre-scaled by dinv[wid] in GEMM epilogue)
        f16x8 v = *(const f16x8*)(tbl + (size_t)wid * 64);
#pragma unroll
        for (int j = 0; j < 8; ++j) acc[j] = (float)v[j];
    }
    const int p0 = rowptr[wid], p1 = rowptr[wid + 1];
    int p = p0;
    for (; p + 4 <= p1; p += 4) {
        int s0 = colv[p], s1 = colv[p + 1], s2 = colv[p + 2], s3 = colv[p + 3];
        f16x8 v0 = *(const f16x8*)(tbl + (size_t)s0 * 64);
        f16x8 v1 = *(const f16x8*)(tbl + (size_t)s1 * 64);
        f16x8 v2 = *(const f16x8*)(tbl + (size_t)s2 * 64);
        f16x8 v3 = *(const f16x8*)(tbl + (size_t)s3 * 64);
#pragma unroll
        for (int j = 0; j < 8; ++j)
            acc[j] += ((float)v0[j] + (float)v1[j]) + ((float)v2[j] + (float)v3[j]);
    }
    for (; p < p1; ++p) {
        f16x8 v = *(const f16x8*)(tbl + (size_t)colv[p] * 64);
#pragma unroll
        for (int j = 0; j < 8; ++j) acc[j] += (float)v[j];
    }
    const float di = dinv[wid];
    float r[8];
#pragma unroll
    for (int j = 0; j < 8; ++j) {
        float t = di * acc[j] + bias[slice * 64 + fb + j];
        r[j] = t > 0.f ? t : 0.f;
    }
    const size_t o = (size_t)wid * F + slice * 64 + fb;
    if constexpr (SPLIT) {
        f16x8 hv, lv;
#pragma unroll
        for (int j = 0; j < 8; ++j) { h2 s = split2h(r[j]); hv[j] = s.h; lv[j] = s.l; }
        *(f16x8*)(outh + o) = hv;
        *(f16x8*)(outl + o) = lv;
    } else {
        float* op = outf + o;
        *(float4*)(op)     = make_float4(r[0], r[1], r[2], r[3]);
        *(float4*)(op + 4) = make_float4(r[4], r[5], r[6], r[7]);
    }
}

extern "C" void kernel_launch(void* const* d_in, const int* in_sizes, int n_in,
                              void* d_out, int out_size, void* d_ws, size_t ws_size,
                              hipStream_t stream) {
    const float* x  = (const float*)d_in[0];
    const int*   ei = (const int*)d_in[1];
    const float* W1 = (const float*)d_in[2];
    const float* b1 = (const float*)d_in[3];
    const float* W2 = (const float*)d_in[4];
    const float* b2 = (const float*)d_in[5];

    const int HID = in_sizes[3];            // 256
    const int IN  = in_sizes[2] / HID;      // 256
    const int OUT = in_sizes[5];            // 128
    const int N   = in_sizes[0] / IN;       // 50000
    const int E   = in_sizes[1] / 2;        // 800000

    const int* src = ei;
    const int* dst = ei + E;

    char* wsb = (char*)d_ws;
    size_t off = 0;
    auto carve = [&](size_t bytes) -> char* {
        char* p = wsb + off;
        off += (bytes + 255) & ~(size_t)255;
        return p;
    };
    _Float16* xh  = (_Float16*)carve((size_t)N * IN * 2);   // also h1h
    _Float16* xl  = (_Float16*)carve((size_t)N * IN * 2);   // also h1l
    _Float16* hsb = (_Float16*)carve((size_t)N * HID * 2);  // slice-major [4][N][64]
    _Float16* gsb = (_Float16*)carve((size_t)N * OUT * 2);  // slice-major [2][N][64]
    float* dinv   = (float*)carve((size_t)N * 4);
    int*   rowptr = (int*)carve((size_t)(N + 1) * 4);
    int*   cnt    = (int*)carve((size_t)N * 4);
    int*   part   = (int*)carve(1024);
    int*   colv   = (int*)carve((size_t)E * 4);
    _Float16* W1Th = (_Float16*)carve((size_t)IN * HID * 2);
    _Float16* W2Th = (_Float16*)carve((size_t)HID * OUT * 2);
    _Float16* h1h = xh;  // reuse: x planes dead after gemm1
    _Float16* h1l = xl;
    (void)ws_size; (void)n_in; (void)out_size;

    const int nbN = (N + 255) / 256;   // 196 (<=256 required by k_scan_partial)
    const int nbE = (E + 255) / 256;
    const int ybN = (N + 31) / 32;     // 1563: one 8-lane subgroup per node

    // CSR + dinv
    k_fill_i32<<<nbN, 256, 0, stream>>>(cnt, 0, N);
    k_count<<<nbE, 256, 0, stream>>>(dst, cnt, E);
    k_scan_block<<<nbN, 256, 0, stream>>>(cnt, rowptr, part, dinv, N);
    k_scan_partial<<<1, 256, 0, stream>>>(part, nbN);
    k_scan_add<<<nbN, 256, 0, stream>>>(rowptr, part, cnt, N, E);
    k_fill_col<<<nbE, 256, 0, stream>>>(src, dst, rowptr, cnt, colv, E);

    // operand prep
    k_split<<<2048, 256, 0, stream>>>(x, xh, xl, (N * IN) / 4);
    k_thalf<<<dim3(HID / 64, IN / 64), 256, 0, stream>>>(W1, W1Th, IN, HID);
    k_thalf<<<dim3(OUT / 64, HID / 64), 256, 0, stream>>>(W2, W2Th, HID, OUT);

    // layer 1
    k_gemm_split<<<dim3((N + 127) / 128, HID / 128), 256, 0, stream>>>(
        xh, xl, W1Th, dinv, hsb, N, IN, HID);
    k_agg_gr<4, true><<<dim3(4, ybN), 256, 0, stream>>>(
        hsb, rowptr, colv, dinv, b1, nullptr, h1h, h1l, N);
    // layer 2
    k_gemm_split<<<dim3((N + 127) / 128, OUT / 128), 256, 0, stream>>>(
        h1h, h1l, W2Th, dinv, gsb, N, HID, OUT);
    k_agg_gr<2, false><<<dim3(2, ybN), 256, 0, stream>>>(
        gsb, rowptr, colv, dinv, b2, (float*)d_out, nullptr, nullptr, N);
}

// Round 9
// 226.313 us; speedup vs baseline: 1.7730x; 1.1147x over previous
//
#include <hip/hip_runtime.h>
#include <hip/hip_bf16.h>
#include <cstdint>
#include <cstddef>

// GCN 2-layer forward, MI355X (gfx950).
//   CSR build -> rowptr/colv + dinv   (memset + 5 kernels)
//   W1,W2 -> transposed fp16-hi planes (one merged kernel)
//   hs = fp16( dinv[m]*(x @ W1h) )   gemm1: A = fp32 x, Dekker-split IN-KERNEL
//                                    (reg->swizzled ds_write), B via gll;
//                                    BK=64, 2-term fp16 MFMA; slice-major out
//   h1 planes = fp16split( relu(dinv*rowsum(hs)+b1) )   agg (R8 structure)
//   gs = fp16( dinv[m]*(h1 @ W2h) )  gemm2: all 3 planes via gll, BK=64
//   out = relu( dinv*rowsum(gs)+b2 ) fp32
//
// Swizzle discipline (G21): LDS layout = linear rows of 8x16B slots; slot
// permutation slot^=(row&7) applied on the WRITE side (ds_write offset for
// reg-staged A; pre-swizzled GLOBAL address for global_load_lds planes) and
// identically on the ds_read side. 16 lanes reading one slot-column spread
// 2-way across bank-quads (free, m136).

typedef float f32x4 __attribute__((ext_vector_type(4)));
typedef _Float16 f16x8 __attribute__((ext_vector_type(8)));
typedef _Float16 f16x4 __attribute__((ext_vector_type(4)));

#define AS1 __attribute__((address_space(1)))
#define AS3 __attribute__((address_space(3)))

struct h2 { _Float16 h, l; };
// fp16 Dekker split: f = (float)h + (float)l + O(2^-22 rel)
__device__ __forceinline__ h2 split2h(float f) {
    h2 r;
    r.h = (_Float16)f;
    r.l = (_Float16)(f - (float)r.h);
    return r;
}

// ---------------- CSR build ----------------
__global__ __launch_bounds__(256) void k_count(const int* __restrict__ dst,
                                               int* __restrict__ cnt, int E) {
    int e = blockIdx.x * 256 + threadIdx.x;
    if (e < E) atomicAdd(&cnt[dst[e]], 1);
}

__global__ __launch_bounds__(256) void k_scan_block(const int* __restrict__ cnt,
                                                    int* __restrict__ rowptr,
                                                    int* __restrict__ partial,
                                                    float* __restrict__ dinv, int n) {
    __shared__ int s[256];
    int i = blockIdx.x * 256 + threadIdx.x;
    int v = (i < n) ? cnt[i] : 0;
    if (i < n) dinv[i] = rsqrtf((float)(v + 1));
    s[threadIdx.x] = v;
    __syncthreads();
    for (int off = 1; off < 256; off <<= 1) {
        int t = (threadIdx.x >= off) ? s[threadIdx.x - off] : 0;
        __syncthreads();
        s[threadIdx.x] += t;
        __syncthreads();
    }
    if (i < n) rowptr[i] = s[threadIdx.x] - v;
    if (threadIdx.x == 255) partial[blockIdx.x] = s[255];
}

__global__ __launch_bounds__(256) void k_scan_partial(int* __restrict__ partial, int nb) {
    __shared__ int s[256];
    int v = (threadIdx.x < nb) ? partial[threadIdx.x] : 0;
    s[threadIdx.x] = v;
    __syncthreads();
    for (int off = 1; off < 256; off <<= 1) {
        int t = (threadIdx.x >= off) ? s[threadIdx.x - off] : 0;
        __syncthreads();
        s[threadIdx.x] += t;
        __syncthreads();
    }
    if (threadIdx.x < nb) partial[threadIdx.x] = s[threadIdx.x] - v;
}

// also zeroes cnt (cursor reuse) — cnt dead after k_scan_block
__global__ __launch_bounds__(256) void k_scan_add(int* __restrict__ rowptr,
                                                  const int* __restrict__ partial,
                                                  int* __restrict__ cnt,
                                                  int n, int e) {
    int i = blockIdx.x * 256 + threadIdx.x;
    if (i < n) { rowptr[i] += partial[blockIdx.x]; cnt[i] = 0; }
    if (i == 0) rowptr[n] = e;
}

__global__ __launch_bounds__(256) void k_fill_col(const int* __restrict__ src,
                                                  const int* __restrict__ dst,
                                                  const int* __restrict__ rowptr,
                                                  int* __restrict__ cur,
                                                  int* __restrict__ colv, int E) {
    int e = blockIdx.x * 256 + threadIdx.x;
    if (e < E) {
        int d = dst[e];
        int p = rowptr[d] + atomicAdd(&cur[d], 1);
        colv[p] = src[e];
    }
}

// ---------------- merged transpose+fp16: W1[R1][C1]->T1[C1][R1], W2 likewise
__global__ __launch_bounds__(256) void k_thalf2(const float* __restrict__ W1,
                                                _Float16* __restrict__ T1,
                                                const float* __restrict__ W2,
                                                _Float16* __restrict__ T2,
                                                int R1, int C1, int R2, int C2) {
    const float* src; _Float16* dh; int R, C;
    if (blockIdx.z == 0) { src = W1; dh = T1; R = R1; C = C1; }
    else                 { src = W2; dh = T2; R = R2; C = C2; }
    if ((int)blockIdx.x * 64 >= C || (int)blockIdx.y * 64 >= R) return;
    __shared__ float tile[64][65];
    int r0 = blockIdx.y * 64, c0 = blockIdx.x * 64;
    for (int i = threadIdx.x; i < 4096; i += 256) {
        int r = i >> 6, c = i & 63;
        tile[r][c] = src[(size_t)(r0 + r) * C + c0 + c];
    }
    __syncthreads();
    for (int i = threadIdx.x; i < 4096; i += 256) {
        int r = i >> 6, c = i & 63;
        dh[(size_t)(c0 + r) * R + r0 + c] = (_Float16)tile[c][r];
    }
}

// ---------------- gemm1: A = fp32 x (in-kernel split), B = fp16 planes -------
// C[slice-major] = fp16(scale[m] * ((Ah+Al) @ Bh^T)); tile 128x128, BK=64,
// 4 waves. LDS: Ah,Al,Bh [128][64] fp16 = 48 KB.
__global__ __launch_bounds__(256) void k_gemm1(const float* __restrict__ X,
                                               const _Float16* __restrict__ B,
                                               const float* __restrict__ scale,
                                               _Float16* __restrict__ C,
                                               int M, int K, int Nc) {
    __shared__ __align__(16) _Float16 lds[3 * 128 * 64];  // Ah | Al | Bh
    _Float16* Ahl = lds;
    _Float16* All = lds + 8192;
    _Float16* Bhl = lds + 16384;
    const int tid = threadIdx.x;
    const int m0 = blockIdx.x * 128, n0 = blockIdx.y * 128;
    const int w = tid >> 6, lane = tid & 63;
    const int wr = w >> 1, wc = w & 1;
    const int fr = lane & 15, kg = lane >> 4;

    const int arow = tid >> 1;            // staging row 0..127
    const int kf = (tid & 1) * 32;        // float offset within BK
    int rgA = m0 + arow; if (rgA >= M) rgA = M - 1;
    const float* ap0 = X + (size_t)rgA * K + kf;

    f32x4 acc[4][4] = {};

    for (int k0 = 0; k0 < K; k0 += 64) {
        // B plane: async global->LDS, address-side swizzle
#pragma unroll
        for (int c = 0; c < 4; ++c) {
            const int r = c * 4 + w;              // 0..15, wave-uniform
            const int wch = r * 64 + lane;        // 0..1023
            const int row = wch >> 3, slot = wch & 7;
            const _Float16* gp = B + (size_t)(n0 + row) * K + k0 + ((slot ^ (row & 7)) << 3);
            __builtin_amdgcn_global_load_lds((const AS1 void*)gp,
                                             (AS3 void*)(Bhl + (size_t)r * 512), 16, 0, 0);
        }
        // A: fp32 load -> split -> swizzled ds_write
        {
            const float* ap = ap0 + k0;
            float fv[32];
#pragma unroll
            for (int c = 0; c < 8; ++c) {
                float4 q = *(const float4*)(ap + c * 4);
                fv[c * 4 + 0] = q.x; fv[c * 4 + 1] = q.y;
                fv[c * 4 + 2] = q.z; fv[c * 4 + 3] = q.w;
            }
#pragma unroll
            for (int c2 = 0; c2 < 4; ++c2) {
                f16x8 hv, lv;
#pragma unroll
                for (int j = 0; j < 8; ++j) {
                    h2 s = split2h(fv[c2 * 8 + j]);
                    hv[j] = s.h; lv[j] = s.l;
                }
                const int s = (tid & 1) * 4 + c2;
                const int off = arow * 64 + ((s ^ (arow & 7)) << 3);
                *(f16x8*)&Ahl[off] = hv;
                *(f16x8*)&All[off] = lv;
            }
        }
        __syncthreads();
#pragma unroll
        for (int kc = 0; kc < 2; ++kc) {
            f16x8 a_h[4], a_l[4], b_h[4];
#pragma unroll
            for (int i = 0; i < 4; ++i) {
                const int ar = wr * 64 + i * 16 + fr;
                const int sa = ((kc * 4 + kg) ^ (ar & 7)) << 3;
                a_h[i] = *(const f16x8*)&Ahl[ar * 64 + sa];
                a_l[i] = *(const f16x8*)&All[ar * 64 + sa];
                const int br = wc * 64 + i * 16 + fr;
                const int sb = ((kc * 4 + kg) ^ (br & 7)) << 3;
                b_h[i] = *(const f16x8*)&Bhl[br * 64 + sb];
            }
#pragma unroll
            for (int i = 0; i < 4; ++i)
#pragma unroll
                for (int j = 0; j < 4; ++j) {
                    acc[i][j] = __builtin_amdgcn_mfma_f32_16x16x32_f16(a_h[i], b_h[j], acc[i][j], 0, 0, 0);
                    acc[i][j] = __builtin_amdgcn_mfma_f32_16x16x32_f16(a_l[i], b_h[j], acc[i][j], 0, 0, 0);
                }
        }
        __syncthreads();
    }
    // C/D layout: col=lane&15, row=(lane>>4)*4+reg (m89/m91); slice-major store.
#pragma unroll
    for (int i = 0; i < 4; ++i) {
        const int rbase = m0 + wr * 64 + i * 16 + (lane >> 4) * 4;
#pragma unroll
        for (int r = 0; r < 4; ++r) {
            const int row = rbase + r;
            if (row < M) {
                const float s = scale[row];
#pragma unroll
                for (int j = 0; j < 4; ++j) {
                    const int col = n0 + wc * 64 + j * 16 + fr;
                    const size_t o = ((size_t)(col >> 6) * M + row) * 64 + (col & 63);
                    C[o] = (_Float16)(acc[i][j][r] * s);
                }
            }
        }
    }
}

// ---------------- gemm2: all three planes fp16 via global_load_lds ----------
__global__ __launch_bounds__(256) void k_gemm2(const _Float16* __restrict__ Ahp,
                                               const _Float16* __restrict__ Alp,
                                               const _Float16* __restrict__ Bp,
                                               const float* __restrict__ scale,
                                               _Float16* __restrict__ C,
                                               int M, int K, int Nc) {
    __shared__ __align__(16) _Float16 lds[3 * 128 * 64];  // Ah | Al | Bh
    const int tid = threadIdx.x;
    const int m0 = blockIdx.x * 128, n0 = blockIdx.y * 128;
    const int w = tid >> 6, lane = tid & 63;
    const int wr = w >> 1, wc = w & 1;
    const int fr = lane & 15, kg = lane >> 4;

    f32x4 acc[4][4] = {};

    for (int k0 = 0; k0 < K; k0 += 64) {
#pragma unroll
        for (int c = 0; c < 12; ++c) {
            const int r = c * 4 + w;              // 0..47, wave-uniform
            const int p = r >> 4;                 // plane, wave-uniform
            const int wch = (r & 15) * 64 + lane; // 0..1023
            const int row = wch >> 3, slot = wch & 7;
            const int swz = (slot ^ (row & 7)) << 3;
            const _Float16* gp;
            if (p == 0) {
                int rg = m0 + row; if (rg >= M) rg = M - 1;
                gp = Ahp + (size_t)rg * K + k0 + swz;
            } else if (p == 1) {
                int rg = m0 + row; if (rg >= M) rg = M - 1;
                gp = Alp + (size_t)rg * K + k0 + swz;
            } else {
                gp = Bp + (size_t)(n0 + row) * K + k0 + swz;
            }
            __builtin_amdgcn_global_load_lds((const AS1 void*)gp,
                                             (AS3 void*)(lds + (size_t)r * 512), 16, 0, 0);
        }
        __syncthreads();
#pragma unroll
        for (int kc = 0; kc < 2; ++kc) {
            f16x8 a_h[4], a_l[4], b_h[4];
#pragma unroll
            for (int i = 0; i < 4; ++i) {
                const int ar = wr * 64 + i * 16 + fr;
                const int sa = ((kc * 4 + kg) ^ (ar & 7)) << 3;
                a_h[i] = *(const f16x8*)&lds[ar * 64 + sa];
                a_l[i] = *(const f16x8*)&lds[8192 + ar * 64 + sa];
                const int br = wc * 64 + i * 16 + fr;
                const int sb = ((kc * 4 + kg) ^ (br & 7)) << 3;
                b_h[i] = *(const f16x8*)&lds[16384 + br * 64 + sb];
            }
#pragma unroll
            for (int i = 0; i < 4; ++i)
#pragma unroll
                for (int j = 0; j < 4; ++j) {
                    acc[i][j] = __builtin_amdgcn_mfma_f32_16x16x32_f16(a_h[i], b_h[j], acc[i][j], 0, 0, 0);
                    acc[i][j] = __builtin_amdgcn_mfma_f32_16x16x32_f16(a_l[i], b_h[j], acc[i][j], 0, 0, 0);
                }
        }
        __syncthreads();
    }
#pragma unroll
    for (int i = 0; i < 4; ++i) {
        const int rbase = m0 + wr * 64 + i * 16 + (lane >> 4) * 4;
#pragma unroll
        for (int r = 0; r < 4; ++r) {
            const int row = rbase + r;
            if (row < M) {
                const float s = scale[row];
#pragma unroll
                for (int j = 0; j < 4; ++j) {
                    const int col = n0 + wc * 64 + j * 16 + fr;
                    const size_t o = ((size_t)(col >> 6) * M + row) * 64 + (col & 63);
                    C[o] = (_Float16)(acc[i][j][r] * s);
                }
            }
        }
    }
}

// ---------------- aggregation: 128B granules, XCD-pinned slices (R8) --------
template <int NSLICE, bool SPLIT>
__global__ __launch_bounds__(256) void k_agg_gr(const _Float16* __restrict__ tbl0,
                                                const int* __restrict__ rowptr,
                                                const int* __restrict__ colv,
                                                const float* __restrict__ dinv,
                                                const float* __restrict__ bias,
                                                float* __restrict__ outf,
                                                _Float16* __restrict__ outh,
                                                _Float16* __restrict__ outl, int n) {
    constexpr int F = NSLICE * 64;
    const int slice = blockIdx.x;
    const int g = threadIdx.x >> 3;      // subgroup 0..31 = node within block
    const int li = threadIdx.x & 7;
    const int fb = li * 8;               // feature offset within slice
    const int wid = blockIdx.y * 32 + g;
    if (wid >= n) return;
    const _Float16* tbl = tbl0 + (size_t)slice * n * 64 + fb;

    float acc[8];
    {   // self row (pre-scaled by dinv[wid] in GEMM epilogue)
        f16x8 v = *(const f16x8*)(tbl + (size_t)wid * 64);
#pragma unroll
        for (int j = 0; j < 8; ++j) acc[j] = (float)v[j];
    }
    const int p0 = rowptr[wid], p1 = rowptr[wid + 1];
    int p = p0;
    for (; p + 4 <= p1; p += 4) {
        int s0 = colv[p], s1 = colv[p + 1], s2 = colv[p + 2], s3 = colv[p + 3];
        f16x8 v0 = *(const f16x8*)(tbl + (size_t)s0 * 64);
        f16x8 v1 = *(const f16x8*)(tbl + (size_t)s1 * 64);
        f16x8 v2 = *(const f16x8*)(tbl + (size_t)s2 * 64);
        f16x8 v3 = *(const f16x8*)(tbl + (size_t)s3 * 64);
#pragma unroll
        for (int j = 0; j < 8; ++j)
            acc[j] += ((float)v0[j] + (float)v1[j]) + ((float)v2[j] + (float)v3[j]);
    }
    for (; p < p1; ++p) {
        f16x8 v = *(const f16x8*)(tbl + (size_t)colv[p] * 64);
#pragma unroll
        for (int j = 0; j < 8; ++j) acc[j] += (float)v[j];
    }
    const float di = dinv[wid];
    float r[8];
#pragma unroll
    for (int j = 0; j < 8; ++j) {
        float t = di * acc[j] + bias[slice * 64 + fb + j];
        r[j] = t > 0.f ? t : 0.f;
    }
    const size_t o = (size_t)wid * F + slice * 64 + fb;
    if constexpr (SPLIT) {
        f16x8 hv, lv;
#pragma unroll
        for (int j = 0; j < 8; ++j) { h2 s = split2h(r[j]); hv[j] = s.h; lv[j] = s.l; }
        *(f16x8*)(outh + o) = hv;
        *(f16x8*)(outl + o) = lv;
    } else {
        float* op = outf + o;
        *(float4*)(op)     = make_float4(r[0], r[1], r[2], r[3]);
        *(float4*)(op + 4) = make_float4(r[4], r[5], r[6], r[7]);
    }
}

extern "C" void kernel_launch(void* const* d_in, const int* in_sizes, int n_in,
                              void* d_out, int out_size, void* d_ws, size_t ws_size,
                              hipStream_t stream) {
    const float* x  = (const float*)d_in[0];
    const int*   ei = (const int*)d_in[1];
    const float* W1 = (const float*)d_in[2];
    const float* b1 = (const float*)d_in[3];
    const float* W2 = (const float*)d_in[4];
    const float* b2 = (const float*)d_in[5];

    const int HID = in_sizes[3];            // 256
    const int IN  = in_sizes[2] / HID;      // 256
    const int OUT = in_sizes[5];            // 128
    const int N   = in_sizes[0] / IN;       // 50000
    const int E   = in_sizes[1] / 2;        // 800000

    const int* src = ei;
    const int* dst = ei + E;

    char* wsb = (char*)d_ws;
    size_t off = 0;
    auto carve = [&](size_t bytes) -> char* {
        char* p = wsb + off;
        off += (bytes + 255) & ~(size_t)255;
        return p;
    };
    _Float16* h1h = (_Float16*)carve((size_t)N * HID * 2);
    _Float16* h1l = (_Float16*)carve((size_t)N * HID * 2);
    _Float16* hsb = (_Float16*)carve((size_t)N * HID * 2);  // slice-major [4][N][64]
    _Float16* gsb = (_Float16*)carve((size_t)N * OUT * 2);  // slice-major [2][N][64]
    float* dinv   = (float*)carve((size_t)N * 4);
    int*   rowptr = (int*)carve((size_t)(N + 1) * 4);
    int*   cnt    = (int*)carve((size_t)N * 4);
    int*   part   = (int*)carve(1024);
    int*   colv   = (int*)carve((size_t)E * 4);
    _Float16* W1Th = (_Float16*)carve((size_t)IN * HID * 2);
    _Float16* W2Th = (_Float16*)carve((size_t)HID * OUT * 2);
    (void)ws_size; (void)n_in; (void)out_size;

    const int nbN = (N + 255) / 256;   // 196 (<=256 required by k_scan_partial)
    const int nbE = (E + 255) / 256;
    const int ybN = (N + 31) / 32;     // one 8-lane subgroup per node

    // CSR + dinv (memset replaces fill kernel)
    hipMemsetAsync(cnt, 0, (size_t)N * 4, stream);
    k_count<<<nbE, 256, 0, stream>>>(dst, cnt, E);
    k_scan_block<<<nbN, 256, 0, stream>>>(cnt, rowptr, part, dinv, N);
    k_scan_partial<<<1, 256, 0, stream>>>(part, nbN);
    k_scan_add<<<nbN, 256, 0, stream>>>(rowptr, part, cnt, N, E);
    k_fill_col<<<nbE, 256, 0, stream>>>(src, dst, rowptr, cnt, colv, E);

    // merged weight transposes (fp16-hi planes)
    k_thalf2<<<dim3(4, 4, 2), 256, 0, stream>>>(W1, W1Th, W2, W2Th, IN, HID, HID, OUT);

    // layer 1 (x split fused into gemm1)
    k_gemm1<<<dim3((N + 127) / 128, HID / 128), 256, 0, stream>>>(
        x, W1Th, dinv, hsb, N, IN, HID);
    k_agg_gr<4, true><<<dim3(4, ybN), 256, 0, stream>>>(
        hsb, rowptr, colv, dinv, b1, nullptr, h1h, h1l, N);
    // layer 2
    k_gemm2<<<dim3((N + 127) / 128, OUT / 128), 256, 0, stream>>>(
        h1h, h1l, W2Th, dinv, gsb, N, HID, OUT);
    k_agg_gr<2, false><<<dim3(2, ybN), 256, 0, stream>>>(
        gsb, rowptr, colv, dinv, b2, (float*)d_out, nullptr, nullptr, N);
}